// Round 1
// baseline (11479.102 us; speedup 1.0000x reference)
//
#include <hip/hip_runtime.h>
#include <stdint.h>

// RNN_60292750901480: h_t = tanh(x_t@Wx + b + h_{t-1}@Wh), N=128,T=512,D=H=512, fp32.
// Phase 1: xW = x@Wx+b via split-bf16 MFMA (fp32-quality) into d_out.
// Phase 2: persistent kernel, 8 row-clusters x 16 col-blocks, Wh B-frags in VGPRs,
//          per-cluster flag sync (agent-scope atomics), h double-buffered in d_ws.

typedef __attribute__((ext_vector_type(8))) short short8;
typedef __attribute__((ext_vector_type(4))) float f32x4;

#define DEV static __device__ __forceinline__

DEV unsigned short f2bf(float f) {
    uint32_t u = __builtin_bit_cast(uint32_t, f);
    u += 0x7FFFu + ((u >> 16) & 1u);   // round-to-nearest-even
    return (unsigned short)(u >> 16);
}
DEV float bf2f(unsigned short h) {
    uint32_t u = ((uint32_t)h) << 16;
    return __builtin_bit_cast(float, u);
}
DEV void split8(const float* v, short8& hi, short8& lo) {
    #pragma unroll
    for (int j = 0; j < 8; ++j) {
        unsigned short h = f2bf(v[j]);
        float r = v[j] - bf2f(h);       // exact
        hi[j] = (short)h;
        lo[j] = (short)f2bf(r);
    }
}

// ---------------- Phase 1: xW = x @ Wx + b  (M=65536, K=512, N=512) ----------------
// 128x128 tile per wg, 4 waves of 64x64, split-bf16 via K-chunked hi/lo LDS staging.
__global__ __launch_bounds__(256) void xw_gemm(
    const float* __restrict__ x, const float* __restrict__ Wx,
    const float* __restrict__ bias, float* __restrict__ out)
{
    // A cells: [rowtile(8)][kblk(4)][16r][8k]; B cells: [coltile(8)][kblk(4)][16c][8k]
    __shared__ short Ahi[128 * 32], Alo[128 * 32];
    __shared__ short Bhi[32 * 128], Blo[32 * 128];

    const int bid = blockIdx.x;
    const int m0 = (bid >> 2) * 128;
    const int n0 = (bid & 3) * 128;
    const int tid = threadIdx.x;
    const int lane = tid & 63;
    const int wave = tid >> 6;
    const int wr = (wave >> 1) * 64;   // wave row offset
    const int wc = (wave & 1) * 64;    // wave col offset

    f32x4 acc[4][4];
    #pragma unroll
    for (int i = 0; i < 4; ++i)
        #pragma unroll
        for (int j = 0; j < 4; ++j)
            acc[i][j] = (f32x4){0.f, 0.f, 0.f, 0.f};

    for (int kc = 0; kc < 512; kc += 32) {
        __syncthreads();   // protect LDS from previous iteration's readers
        // stage x[128 rows x 32 k] -> hi/lo, A-fragment cell layout
        #pragma unroll
        for (int cc = 0; cc < 2; ++cc) {
            int c = tid + cc * 256;
            int row = c >> 2, kb = c & 3;
            const float* src = x + (size_t)(m0 + row) * 512 + kc + kb * 8;
            alignas(16) float v[8];
            *(float4*)(v)     = *(const float4*)src;
            *(float4*)(v + 4) = *(const float4*)(src + 4);
            short8 h8, l8;
            split8(v, h8, l8);
            int cell = ((row >> 4) * 4 + kb) * 16 + (row & 15);
            *(short8*)&Ahi[cell * 8] = h8;
            *(short8*)&Alo[cell * 8] = l8;
        }
        // stage Wx[32 k x 128 cols] -> hi/lo, B-fragment cell layout
        {
            int cell = tid >> 3, j = tid & 7;      // cell: CT(8) x kb(4)
            int ct = cell >> 2, kb = cell & 3;
            const float* src = Wx + (size_t)(kc + kb * 8 + j) * 512 + n0 + ct * 16;
            #pragma unroll
            for (int c16 = 0; c16 < 16; ++c16) {
                float v = src[c16];
                unsigned short h = f2bf(v);
                int idx = (cell * 16 + c16) * 8 + j;
                Bhi[idx] = (short)h;
                Blo[idx] = (short)f2bf(v - bf2f(h));
            }
        }
        __syncthreads();

        short8 bh[4], bl[4];
        #pragma unroll
        for (int ct = 0; ct < 4; ++ct) {
            int CT = (wc >> 4) + ct;
            bh[ct] = *(const short8*)&Bhi[CT * 512 + lane * 8];
            bl[ct] = *(const short8*)&Blo[CT * 512 + lane * 8];
        }
        #pragma unroll
        for (int rt = 0; rt < 4; ++rt) {
            int RT = (wr >> 4) + rt;
            short8 ah = *(const short8*)&Ahi[RT * 512 + lane * 8];
            short8 al = *(const short8*)&Alo[RT * 512 + lane * 8];
            #pragma unroll
            for (int ct = 0; ct < 4; ++ct) {
                acc[rt][ct] = __builtin_amdgcn_mfma_f32_16x16x32_bf16(ah, bh[ct], acc[rt][ct], 0, 0, 0);
                acc[rt][ct] = __builtin_amdgcn_mfma_f32_16x16x32_bf16(al, bh[ct], acc[rt][ct], 0, 0, 0);
                acc[rt][ct] = __builtin_amdgcn_mfma_f32_16x16x32_bf16(ah, bl[ct], acc[rt][ct], 0, 0, 0);
            }
        }
    }
    // epilogue: D layout col=lane&15, row=(lane>>4)*4+j  (m89-verified)
    #pragma unroll
    for (int ct = 0; ct < 4; ++ct) {
        int col = n0 + wc + ct * 16 + (lane & 15);
        float bv = bias[col];
        #pragma unroll
        for (int rt = 0; rt < 4; ++rt) {
            int rbase = m0 + wr + rt * 16 + (lane >> 4) * 4;
            #pragma unroll
            for (int j = 0; j < 4; ++j)
                out[(size_t)(rbase + j) * 512 + col] = acc[rt][ct][j] + bv;
        }
    }
}

// ---------------- Phase 2: persistent recurrence ----------------
// 128 wgs: cluster r = b%8 (16 batch rows, one XCD by swizzle heuristic),
// col-block c = b/8 (32 cols). 4 waves k-split 128 each; Wh hi/lo B-frags in VGPRs.
__global__ __launch_bounds__(256) void rnn_scan(
    float* xw_out,                      // d_out: xW in, h out (intentionally aliased)
    const float* __restrict__ h0,
    const float* __restrict__ Wh,
    float* __restrict__ hbuf,           // [2][128][512]
    unsigned int* __restrict__ done)    // [512][8] monotonic counters
{
    const int b = blockIdx.x;
    const int r = b & 7;
    const int cblk = b >> 3;
    const int tid = threadIdx.x;
    const int lane = tid & 63;
    const int wave = tid >> 6;
    const int m0 = r * 16;
    const int n0 = cblk * 32;
    const int k0 = wave * 128;

    // Preload Wh B-fragments (hi/lo), resident across all 512 steps.
    short8 Bh[4][2], Bl[4][2];
    #pragma unroll
    for (int s = 0; s < 4; ++s) {
        #pragma unroll
        for (int ct = 0; ct < 2; ++ct) {
            int col = n0 + ct * 16 + (lane & 15);
            #pragma unroll
            for (int j = 0; j < 8; ++j) {
                int k = k0 + s * 32 + (lane >> 4) * 8 + j;
                float v = Wh[(size_t)k * 512 + col];
                unsigned short h = f2bf(v);
                Bh[s][ct][j] = (short)h;
                Bl[s][ct][j] = (short)f2bf(v - bf2f(h));
            }
        }
    }

    __shared__ float red[4][2][16][16];  // k-split partials: [wave][coltile][row][col]

    const int erow = tid >> 5;           // 0..7
    const int ecol = tid & 31;           // 0..31

    for (int t = 0; t < 512; ++t) {
        // Prefetch this step's xW tile (independent of recurrence -> hides HBM latency)
        size_t xi0 = ((size_t)(m0 + erow) * 512 + t) * 512 + n0 + ecol;
        size_t xi1 = ((size_t)(m0 + 8 + erow) * 512 + t) * 512 + n0 + ecol;
        float xw0 = xw_out[xi0];
        float xw1 = xw_out[xi1];

        const float* hsrc;
        if (t == 0) {
            hsrc = h0;
        } else {
            if (tid == 0) {
                while (__hip_atomic_load(&done[(t - 1) * 8 + r], __ATOMIC_ACQUIRE,
                                         __HIP_MEMORY_SCOPE_AGENT) < 16u)
                    __builtin_amdgcn_s_sleep(1);
            }
            __syncthreads();
            __threadfence();   // acquire: invalidate caches before reading peers' h
            hsrc = hbuf + ((t - 1) & 1) * (128 * 512);
        }

        f32x4 acc0 = (f32x4){0.f, 0.f, 0.f, 0.f};
        f32x4 acc1 = (f32x4){0.f, 0.f, 0.f, 0.f};
        const int arow = lane & 15, akb = lane >> 4;
        #pragma unroll
        for (int s = 0; s < 4; ++s) {
            const float* ap = hsrc + (size_t)(m0 + arow) * 512 + k0 + s * 32 + akb * 8;
            alignas(16) float v[8];
            *(float4*)(v)     = *(const float4*)ap;
            *(float4*)(v + 4) = *(const float4*)(ap + 4);
            short8 ah, al;
            split8(v, ah, al);
            acc0 = __builtin_amdgcn_mfma_f32_16x16x32_bf16(ah, Bh[s][0], acc0, 0, 0, 0);
            acc0 = __builtin_amdgcn_mfma_f32_16x16x32_bf16(al, Bh[s][0], acc0, 0, 0, 0);
            acc0 = __builtin_amdgcn_mfma_f32_16x16x32_bf16(ah, Bl[s][0], acc0, 0, 0, 0);
            acc1 = __builtin_amdgcn_mfma_f32_16x16x32_bf16(ah, Bh[s][1], acc1, 0, 0, 0);
            acc1 = __builtin_amdgcn_mfma_f32_16x16x32_bf16(al, Bh[s][1], acc1, 0, 0, 0);
            acc1 = __builtin_amdgcn_mfma_f32_16x16x32_bf16(ah, Bl[s][1], acc1, 0, 0, 0);
        }

        // k-split reduction across the 4 waves via LDS
        #pragma unroll
        for (int ct = 0; ct < 2; ++ct) {
            f32x4 a = ct ? acc1 : acc0;
            #pragma unroll
            for (int j = 0; j < 4; ++j)
                red[wave][ct][(lane >> 4) * 4 + j][lane & 15] = a[j];
        }
        __syncthreads();

        int ctt = ecol >> 4, c16 = ecol & 15;
        float sum0 = red[0][ctt][erow][c16] + red[1][ctt][erow][c16]
                   + red[2][ctt][erow][c16] + red[3][ctt][erow][c16];
        float sum1 = red[0][ctt][erow + 8][c16] + red[1][ctt][erow + 8][c16]
                   + red[2][ctt][erow + 8][c16] + red[3][ctt][erow + 8][c16];
        float hv0 = tanhf(xw0 + sum0);
        float hv1 = tanhf(xw1 + sum1);

        xw_out[xi0] = hv0;                       // final output [N,T,H]
        xw_out[xi1] = hv1;
        float* hb = hbuf + (t & 1) * (128 * 512);
        hb[(m0 + erow) * 512 + n0 + ecol] = hv0;
        hb[(m0 + 8 + erow) * 512 + n0 + ecol] = hv1;

        __threadfence();     // release h stores (agent scope, XCD-safe)
        __syncthreads();     // also separates red reads from next step's writes
        if (tid == 0)
            __hip_atomic_fetch_add(&done[t * 8 + r], 1u, __ATOMIC_RELEASE,
                                   __HIP_MEMORY_SCOPE_AGENT);
    }
}

__global__ void init_done(unsigned int* done) {
    int i = blockIdx.x * 256 + threadIdx.x;
    if (i < 512 * 8) done[i] = 0u;
}

extern "C" void kernel_launch(void* const* d_in, const int* in_sizes, int n_in,
                              void* d_out, int out_size, void* d_ws, size_t ws_size,
                              hipStream_t stream)
{
    const float* x  = (const float*)d_in[0];
    const float* h0 = (const float*)d_in[1];
    const float* Wx = (const float*)d_in[2];
    const float* Wh = (const float*)d_in[3];
    const float* b  = (const float*)d_in[4];
    float* out = (float*)d_out;

    float* hbuf = (float*)d_ws;                                    // 512 KiB
    unsigned int* done = (unsigned int*)((char*)d_ws + (size_t)2 * 128 * 512 * sizeof(float));

    hipLaunchKernelGGL(init_done, dim3(16), dim3(256), 0, stream, done);
    hipLaunchKernelGGL(xw_gemm, dim3(2048), dim3(256), 0, stream, x, Wx, b, out);
    hipLaunchKernelGGL(rnn_scan, dim3(128), dim3(256), 0, stream, out, h0, Wh, hbuf, done);
}

// Round 2
// 3008.634 us; speedup vs baseline: 3.8154x; 3.8154x over previous
//
#include <hip/hip_runtime.h>
#include <stdint.h>

// RNN_60292750901480: h_t = tanh(x_t@Wx + b + h_{t-1}@Wh), N=128,T=512,D=H=512, fp32.
// Phase 1: xW = x@Wx+b via split-bf16 MFMA (fp32-quality) into d_out.
// Phase 2: persistent kernel, 8 row-clusters x 16 col-blocks, Wh B-frags in VGPRs.
// R1 -> R2: __threadfence() (buffer_wbl2/inv cache walks, ~20us/step) replaced by
// per-access agent-scope relaxed atomics on the h/flag path. __syncthreads()'s
// implicit s_waitcnt vmcnt(0) drains coherent stores before the flag publish.

typedef __attribute__((ext_vector_type(8))) short short8;
typedef __attribute__((ext_vector_type(4))) float f32x4;

#define DEV static __device__ __forceinline__

DEV unsigned short f2bf(float f) {
    uint32_t u = __builtin_bit_cast(uint32_t, f);
    u += 0x7FFFu + ((u >> 16) & 1u);   // round-to-nearest-even
    return (unsigned short)(u >> 16);
}
DEV float bf2f(unsigned short h) {
    uint32_t u = ((uint32_t)h) << 16;
    return __builtin_bit_cast(float, u);
}
DEV void split8(const float* v, short8& hi, short8& lo) {
    #pragma unroll
    for (int j = 0; j < 8; ++j) {
        unsigned short h = f2bf(v[j]);
        float r = v[j] - bf2f(h);       // exact
        hi[j] = (short)h;
        lo[j] = (short)f2bf(r);
    }
}

DEV float cohload(const float* p) {
    return __hip_atomic_load(p, __ATOMIC_RELAXED, __HIP_MEMORY_SCOPE_AGENT);
}
DEV void cohstore(float* p, float v) {
    __hip_atomic_store(p, v, __ATOMIC_RELAXED, __HIP_MEMORY_SCOPE_AGENT);
}

// ---------------- Phase 1: xW = x @ Wx + b  (M=65536, K=512, N=512) ----------------
__global__ __launch_bounds__(256) void xw_gemm(
    const float* __restrict__ x, const float* __restrict__ Wx,
    const float* __restrict__ bias, float* __restrict__ out)
{
    __shared__ short Ahi[128 * 32], Alo[128 * 32];
    __shared__ short Bhi[32 * 128], Blo[32 * 128];

    const int bid = blockIdx.x;
    const int m0 = (bid >> 2) * 128;
    const int n0 = (bid & 3) * 128;
    const int tid = threadIdx.x;
    const int lane = tid & 63;
    const int wave = tid >> 6;
    const int wr = (wave >> 1) * 64;
    const int wc = (wave & 1) * 64;

    f32x4 acc[4][4];
    #pragma unroll
    for (int i = 0; i < 4; ++i)
        #pragma unroll
        for (int j = 0; j < 4; ++j)
            acc[i][j] = (f32x4){0.f, 0.f, 0.f, 0.f};

    for (int kc = 0; kc < 512; kc += 32) {
        __syncthreads();
        #pragma unroll
        for (int cc = 0; cc < 2; ++cc) {
            int c = tid + cc * 256;
            int row = c >> 2, kb = c & 3;
            const float* src = x + (size_t)(m0 + row) * 512 + kc + kb * 8;
            alignas(16) float v[8];
            *(float4*)(v)     = *(const float4*)src;
            *(float4*)(v + 4) = *(const float4*)(src + 4);
            short8 h8, l8;
            split8(v, h8, l8);
            int cell = ((row >> 4) * 4 + kb) * 16 + (row & 15);
            *(short8*)&Ahi[cell * 8] = h8;
            *(short8*)&Alo[cell * 8] = l8;
        }
        {
            int cell = tid >> 3, j = tid & 7;
            int ct = cell >> 2, kb = cell & 3;
            const float* src = Wx + (size_t)(kc + kb * 8 + j) * 512 + n0 + ct * 16;
            #pragma unroll
            for (int c16 = 0; c16 < 16; ++c16) {
                float v = src[c16];
                unsigned short h = f2bf(v);
                int idx = (cell * 16 + c16) * 8 + j;
                Bhi[idx] = (short)h;
                Blo[idx] = (short)f2bf(v - bf2f(h));
            }
        }
        __syncthreads();

        short8 bh[4], bl[4];
        #pragma unroll
        for (int ct = 0; ct < 4; ++ct) {
            int CT = (wc >> 4) + ct;
            bh[ct] = *(const short8*)&Bhi[CT * 512 + lane * 8];
            bl[ct] = *(const short8*)&Blo[CT * 512 + lane * 8];
        }
        #pragma unroll
        for (int rt = 0; rt < 4; ++rt) {
            int RT = (wr >> 4) + rt;
            short8 ah = *(const short8*)&Ahi[RT * 512 + lane * 8];
            short8 al = *(const short8*)&Alo[RT * 512 + lane * 8];
            #pragma unroll
            for (int ct = 0; ct < 4; ++ct) {
                acc[rt][ct] = __builtin_amdgcn_mfma_f32_16x16x32_bf16(ah, bh[ct], acc[rt][ct], 0, 0, 0);
                acc[rt][ct] = __builtin_amdgcn_mfma_f32_16x16x32_bf16(al, bh[ct], acc[rt][ct], 0, 0, 0);
                acc[rt][ct] = __builtin_amdgcn_mfma_f32_16x16x32_bf16(ah, bl[ct], acc[rt][ct], 0, 0, 0);
            }
        }
    }
    #pragma unroll
    for (int ct = 0; ct < 4; ++ct) {
        int col = n0 + wc + ct * 16 + (lane & 15);
        float bv = bias[col];
        #pragma unroll
        for (int rt = 0; rt < 4; ++rt) {
            int rbase = m0 + wr + rt * 16 + (lane >> 4) * 4;
            #pragma unroll
            for (int j = 0; j < 4; ++j)
                out[(size_t)(rbase + j) * 512 + col] = acc[rt][ct][j] + bv;
        }
    }
}

// ---------------- Phase 2: persistent recurrence ----------------
// 128 wgs: cluster r = b&7 (16 batch rows), col-block c = b>>3 (32 cols).
// 4 waves k-split 128 each; Wh hi/lo B-frags resident in VGPRs.
// Sync: per-(step,cluster,producer) flag slot, 16-deep ring, equality compare
// (monotonic values -> poison-proof, no init kernel, no RMW contention).
__global__ __launch_bounds__(256) void rnn_scan(
    float* xw_out,                      // d_out: xW in, h out (aliased by design)
    const float* __restrict__ h0,
    const float* __restrict__ Wh,
    float* __restrict__ hbuf,           // [2][128][512] in d_ws
    unsigned int* __restrict__ flags)   // [16][8][16] ring in d_ws
{
    const int b = blockIdx.x;
    const int r = b & 7;
    const int cblk = b >> 3;
    const int tid = threadIdx.x;
    const int lane = tid & 63;
    const int wave = tid >> 6;
    const int m0 = r * 16;
    const int n0 = cblk * 32;
    const int k0 = wave * 128;

    // Preload Wh B-fragments (hi/lo), resident across all 512 steps.
    short8 Bh[4][2], Bl[4][2];
    #pragma unroll
    for (int s = 0; s < 4; ++s) {
        #pragma unroll
        for (int ct = 0; ct < 2; ++ct) {
            int col = n0 + ct * 16 + (lane & 15);
            #pragma unroll
            for (int j = 0; j < 8; ++j) {
                int k = k0 + s * 32 + (lane >> 4) * 8 + j;
                float v = Wh[(size_t)k * 512 + col];
                unsigned short h = f2bf(v);
                Bh[s][ct][j] = (short)h;
                Bl[s][ct][j] = (short)f2bf(v - bf2f(h));
            }
        }
    }

    __shared__ float red[4][2][16][16];  // k-split partials: [wave][coltile][row][col]

    const int erow = tid >> 5;           // 0..7
    const int ecol = tid & 31;           // 0..31
    const int arow = lane & 15, akb = lane >> 4;

    for (int t = 0; t < 512; ++t) {
        // Prefetch this step's xW tile (plain cached loads; wg-private slice)
        size_t xi0 = ((size_t)(m0 + erow) * 512 + t) * 512 + n0 + ecol;
        size_t xi1 = ((size_t)(m0 + 8 + erow) * 512 + t) * 512 + n0 + ecol;
        float xw0 = xw_out[xi0];
        float xw1 = xw_out[xi1];

        const float* hsrc;
        if (t == 0) {
            hsrc = h0;
        } else {
            if (wave == 0) {
                const unsigned int* slot =
                    flags + ((size_t)((t - 1) & 15) * 8 + r) * 16;
                bool okl = (lane >= 16);
                for (;;) {
                    if (!okl)
                        okl = (__hip_atomic_load(&slot[lane], __ATOMIC_RELAXED,
                                                 __HIP_MEMORY_SCOPE_AGENT) == (unsigned)t);
                    if (__all((int)okl)) break;
                    __builtin_amdgcn_s_sleep(1);
                }
            }
            __syncthreads();
            asm volatile("" ::: "memory");
            hsrc = hbuf + ((t - 1) & 1) * (128 * 512);
        }

        // Issue all 32 coherent h loads first (one latency), then split+MFMA.
        float hv[4][8];
        #pragma unroll
        for (int s = 0; s < 4; ++s) {
            const float* ap = hsrc + (size_t)(m0 + arow) * 512 + k0 + s * 32 + akb * 8;
            #pragma unroll
            for (int j = 0; j < 8; ++j)
                hv[s][j] = cohload(&ap[j]);
        }

        f32x4 acc0 = (f32x4){0.f, 0.f, 0.f, 0.f};
        f32x4 acc1 = (f32x4){0.f, 0.f, 0.f, 0.f};
        #pragma unroll
        for (int s = 0; s < 4; ++s) {
            short8 ah, al;
            split8(hv[s], ah, al);
            acc0 = __builtin_amdgcn_mfma_f32_16x16x32_bf16(ah, Bh[s][0], acc0, 0, 0, 0);
            acc0 = __builtin_amdgcn_mfma_f32_16x16x32_bf16(al, Bh[s][0], acc0, 0, 0, 0);
            acc0 = __builtin_amdgcn_mfma_f32_16x16x32_bf16(ah, Bl[s][0], acc0, 0, 0, 0);
            acc1 = __builtin_amdgcn_mfma_f32_16x16x32_bf16(ah, Bh[s][1], acc1, 0, 0, 0);
            acc1 = __builtin_amdgcn_mfma_f32_16x16x32_bf16(al, Bh[s][1], acc1, 0, 0, 0);
            acc1 = __builtin_amdgcn_mfma_f32_16x16x32_bf16(ah, Bl[s][1], acc1, 0, 0, 0);
        }

        // k-split reduction across the 4 waves via LDS
        #pragma unroll
        for (int ct = 0; ct < 2; ++ct) {
            f32x4 a = ct ? acc1 : acc0;
            #pragma unroll
            for (int j = 0; j < 4; ++j)
                red[wave][ct][(lane >> 4) * 4 + j][lane & 15] = a[j];
        }
        __syncthreads();

        int ctt = ecol >> 4, c16 = ecol & 15;
        float sum0 = red[0][ctt][erow][c16] + red[1][ctt][erow][c16]
                   + red[2][ctt][erow][c16] + red[3][ctt][erow][c16];
        float sum1 = red[0][ctt][erow + 8][c16] + red[1][ctt][erow + 8][c16]
                   + red[2][ctt][erow + 8][c16] + red[3][ctt][erow + 8][c16];
        float hv0 = tanhf(xw0 + sum0);
        float hv1 = tanhf(xw1 + sum1);

        xw_out[xi0] = hv0;                       // final output [N,T,H] (plain)
        xw_out[xi1] = hv1;
        float* hb = hbuf + (t & 1) * (128 * 512);
        cohstore(&hb[(m0 + erow) * 512 + n0 + ecol], hv0);
        cohstore(&hb[(m0 + 8 + erow) * 512 + n0 + ecol], hv1);

        // Barrier drains vmcnt (coherent stores reach the coherence point) and
        // also separates `red` reads from next step's writes.
        __syncthreads();
        if (tid == 0)
            __hip_atomic_store(&flags[((size_t)(t & 15) * 8 + r) * 16 + cblk],
                               (unsigned)(t + 1), __ATOMIC_RELAXED,
                               __HIP_MEMORY_SCOPE_AGENT);
    }
}

extern "C" void kernel_launch(void* const* d_in, const int* in_sizes, int n_in,
                              void* d_out, int out_size, void* d_ws, size_t ws_size,
                              hipStream_t stream)
{
    const float* x  = (const float*)d_in[0];
    const float* h0 = (const float*)d_in[1];
    const float* Wx = (const float*)d_in[2];
    const float* Wh = (const float*)d_in[3];
    const float* b  = (const float*)d_in[4];
    float* out = (float*)d_out;

    float* hbuf = (float*)d_ws;                                    // 512 KiB
    unsigned int* flags = (unsigned int*)((char*)d_ws + (size_t)2 * 128 * 512 * sizeof(float)); // 8 KiB ring

    hipLaunchKernelGGL(xw_gemm, dim3(2048), dim3(256), 0, stream, x, Wx, b, out);
    hipLaunchKernelGGL(rnn_scan, dim3(128), dim3(256), 0, stream, out, h0, Wh, hbuf, flags);
}